// Round 4
// baseline (342.068 us; speedup 1.0000x reference)
//
#include <hip/hip_runtime.h>
#include <stdint.h>

#define EMBED 1024
#define NHEAD 16
#define HD    64
#define SEQ   2048
#define BATCH 4

typedef __bf16 bf16x8 __attribute__((ext_vector_type(8)));
typedef __bf16 bf16x4 __attribute__((ext_vector_type(4)));
typedef float  f32x4  __attribute__((ext_vector_type(4)));
typedef unsigned int u32x2 __attribute__((ext_vector_type(2)));

#define GLB(p)  ((__attribute__((address_space(1))) unsigned int*)(p))
#define LDSP(p) ((__attribute__((address_space(3))) unsigned int*)(p))
#define MFMA(a,b,c) __builtin_amdgcn_mfma_f32_16x16x32_bf16(a,b,c,0,0,0)
#define EXP2(x) __builtin_amdgcn_exp2f(x)

// Q pre-scale: (1/sqrt(64)) * log2(e) so attention probs are exp2(S - m) directly
#define QSCALE 0.18033688011112042f

__device__ __forceinline__ unsigned int f2bf(float f) {
    unsigned int u = __float_as_uint(f);
    return (u + 0x7FFFu + ((u >> 16) & 1u)) >> 16;   // RNE fp32->bf16
}
__device__ __forceinline__ unsigned int pack2(float a, float b) {
    return f2bf(a) | (f2bf(b) << 16);
}

// ---------------- x fp32 -> bf16 ----------------
__global__ void k_convert(const float* __restrict__ in, unsigned short* __restrict__ out, int n4) {
    int i = blockIdx.x * 256 + threadIdx.x;
    if (i >= n4) return;
    f32x4 v = ((const f32x4*)in)[i];
    u32x2 w = { pack2(v[0], v[1]), pack2(v[2], v[3]) };
    ((u32x2*)out)[i] = w;
}

// ---------------- W [K][C] fp32 -> Wt [C][K] bf16 (LDS-tiled transpose) ----------------
__global__ void k_transpose(const float* __restrict__ in, unsigned short* __restrict__ out, int K, int C) {
    __shared__ float t[32][33];
    int c0 = blockIdx.x * 32, k0 = blockIdx.y * 32;
    int tid = threadIdx.x;
    #pragma unroll
    for (int i = 0; i < 4; i++) {
        int e = tid + i * 256;
        t[e >> 5][e & 31] = in[(size_t)(k0 + (e >> 5)) * C + c0 + (e & 31)];
    }
    __syncthreads();
    #pragma unroll
    for (int i = 0; i < 4; i++) {
        int e = tid + i * 256;
        int cl = e >> 5, kl = e & 31;
        out[(size_t)(c0 + cl) * K + k0 + kl] = (unsigned short)f2bf(t[kl][cl]);
    }
}

// ---------------- QKV GEMM + bias + RoPE, writes Q,K [bh][n][64] (Q pre-scaled by QSCALE), V^T [bh][64][n] ----------------
__global__ __launch_bounds__(256) void k_qkv(const unsigned short* __restrict__ xb,
    const unsigned short* __restrict__ wt, const float* __restrict__ bias,
    const float* __restrict__ rc, const float* __restrict__ rs,
    unsigned short* __restrict__ Qb, unsigned short* __restrict__ Kb, unsigned short* __restrict__ Vt)
{
    __shared__ unsigned short Al[128 * 32];
    __shared__ unsigned short Bl[128 * 32];
    const int tid = threadIdx.x;
    const int wave = tid >> 6, lane = tid & 63;
    const int l15 = lane & 15, l4 = lane >> 4;
    const int wr = wave >> 1, wc = wave & 1;
    const int tm = blockIdx.y * 128, tc = blockIdx.x * 128;

    const int srow = wave * 32 + (lane >> 2);
    const int scol = (lane & 3) * 8;
    const unsigned short* ga = xb + (size_t)(tm + srow) * EMBED + scol;
    const unsigned short* gb = wt + (size_t)(tc + srow) * EMBED + scol;

    f32x4 acc[4][4] = {};
    for (int k0 = 0; k0 < EMBED; k0 += 32) {
        __syncthreads();
        __builtin_amdgcn_global_load_lds(GLB(ga + k0),               LDSP(Al + wave * 1024),       16, 0, 0);
        __builtin_amdgcn_global_load_lds(GLB(ga + k0 + 16 * EMBED),  LDSP(Al + wave * 1024 + 512), 16, 0, 0);
        __builtin_amdgcn_global_load_lds(GLB(gb + k0),               LDSP(Bl + wave * 1024),       16, 0, 0);
        __builtin_amdgcn_global_load_lds(GLB(gb + k0 + 16 * EMBED),  LDSP(Bl + wave * 1024 + 512), 16, 0, 0);
        __syncthreads();
        bf16x8 af[4], bfr[4];
        #pragma unroll
        for (int m = 0; m < 4; m++) af[m]  = *(const bf16x8*)&Al[(wr * 64 + m * 16 + l15) * 32 + l4 * 8];
        #pragma unroll
        for (int n = 0; n < 4; n++) bfr[n] = *(const bf16x8*)&Bl[(wc * 64 + n * 16 + l15) * 32 + l4 * 8];
        #pragma unroll
        for (int m = 0; m < 4; m++)
            #pragma unroll
            for (int n = 0; n < 4; n++)
                acc[m][n] = MFMA(af[m], bfr[n], acc[m][n]);
    }

    const int cb = tc + wc * 64;          // wave col base; one head per wave
    const int s = cb >> 10;               // 0=q 1=k 2=v
    const int h = (cb >> 6) & 15;
    if (s < 2) {
        #pragma unroll
        for (int m = 0; m < 4; m++)
            #pragma unroll
            for (int j = 0; j < 4; j++) {
                int row = tm + wr * 64 + m * 16 + l4 * 4 + j;
                int b = row >> 11, pos = row & (SEQ - 1);
                float v[4];
                #pragma unroll
                for (int n = 0; n < 4; n++) v[n] = acc[m][n][j] + bias[cb + n * 16 + l15];
                float o[4];
                #pragma unroll
                for (int p = 0; p < 2; p++) {
                    int d1 = p * 16 + l15;
                    float c1 = rc[pos * HD + d1],      s1 = rs[pos * HD + d1];
                    float c2 = rc[pos * HD + d1 + 32], s2 = rs[pos * HD + d1 + 32];
                    o[p]     = v[p] * c1     - v[p + 2] * s1;   // d < 32 : q*cos - q[d+32]*sin
                    o[p + 2] = v[p + 2] * c2 + v[p] * s2;       // d >= 32: q*cos + q[d-32]*sin
                }
                float mul = (s == 0) ? QSCALE : 1.0f;           // fold 1/sqrt(64)*log2e into Q
                unsigned short* dst = (s == 0 ? Qb : Kb) + ((size_t)(b * NHEAD + h) * SEQ + pos) * HD;
                #pragma unroll
                for (int n = 0; n < 4; n++) dst[n * 16 + l15] = (unsigned short)f2bf(o[n] * mul);
            }
    } else {
        #pragma unroll
        for (int m = 0; m < 4; m++) {
            int row0 = tm + wr * 64 + m * 16 + l4 * 4;
            int b = row0 >> 11, pos0 = row0 & (SEQ - 1);
            #pragma unroll
            for (int n = 0; n < 4; n++) {
                float bb = bias[cb + n * 16 + l15];
                u32x2 w = { pack2(acc[m][n][0] + bb, acc[m][n][1] + bb),
                            pack2(acc[m][n][2] + bb, acc[m][n][3] + bb) };
                *(u32x2*)(Vt + ((size_t)(b * NHEAD + h) * HD + n * 16 + l15) * SEQ + pos0) = w;
            }
        }
    }
}

// ---------------- flash attention: Q,K [bh][n][64] (Q pre-scaled), V^T [bh][64][n] -> O [b*n][h*64+d] bf16 ----------------
// Double-buffered K/V staging, 1 raw s_barrier per tile, counted vmcnt (T3+T4).
__global__ __launch_bounds__(256) void k_attn(const unsigned short* __restrict__ Qb,
    const unsigned short* __restrict__ Kb, const unsigned short* __restrict__ Vt,
    unsigned short* __restrict__ O)
{
    __shared__ unsigned short Kl[2][64 * 64];   // [buf][k][d], XOR-swizzled rows (128B)
    __shared__ unsigned short Vl[2][64 * 64];   // [buf][d][tok], XOR-swizzled
    __shared__ unsigned short Pl[128 * 64];     // per-wave P [q][k], XOR-swizzled
    const int tid = threadIdx.x, wave = tid >> 6, lane = tid & 63;
    const int l15 = lane & 15, l4 = lane >> 4;
    const int bh = blockIdx.y;
    const int b = bh >> 4, h = bh & 15;
    const int q0 = blockIdx.x * 128 + wave * 32;

    // Q fragments in registers (B-operand: lane&15 = q row, walks d)
    const unsigned short* Qg = Qb + ((size_t)bh * SEQ + q0) * HD;
    bf16x8 qf[2][2];
    #pragma unroll
    for (int qb = 0; qb < 2; qb++)
        #pragma unroll
        for (int ds = 0; ds < 2; ds++)
            qf[qb][ds] = *(const bf16x8*)(Qg + (qb * 16 + l15) * HD + ds * 32 + l4 * 8);

    // staging: pre-swizzled global source so linear global_load_lds yields swizzled LDS (rule 21)
    const int srow = lane >> 3;                       // 0..7
    const int selem = ((lane & 7) * 8) ^ ((srow & 7) * 8);
    const unsigned short* kg = Kb + (size_t)bh * SEQ * HD + (size_t)(wave * 16 + srow) * HD + selem;
    const unsigned short* vg = Vt + (size_t)bh * HD * SEQ + (size_t)(wave * 16 + srow) * SEQ + selem;

#define ISSUE(kt_, bi_) do { \
    __builtin_amdgcn_global_load_lds(GLB(kg + (size_t)(kt_) * HD),       LDSP(&Kl[bi_][0] + wave * 1024),       16, 0, 0); \
    __builtin_amdgcn_global_load_lds(GLB(kg + (size_t)((kt_) + 8) * HD), LDSP(&Kl[bi_][0] + wave * 1024 + 512), 16, 0, 0); \
    __builtin_amdgcn_global_load_lds(GLB(vg + (kt_)),                    LDSP(&Vl[bi_][0] + wave * 1024),       16, 0, 0); \
    __builtin_amdgcn_global_load_lds(GLB(vg + 8 * SEQ + (kt_)),          LDSP(&Vl[bi_][0] + wave * 1024 + 512), 16, 0, 0); \
} while (0)

    f32x4 accO[2][4] = {};
    float mst[2] = { -1e30f, -1e30f }, lst[2] = { 0.f, 0.f };

    ISSUE(0, 0);                                     // prologue: tile 0 in flight

    for (int kt = 0; kt < SEQ; kt += 64) {
        const int cur = (kt >> 6) & 1;
        // single barrier: all waves finished reading buf[cur^1] (tile kt-64) -> safe to overwrite
        __builtin_amdgcn_s_barrier();
        if (kt + 64 < SEQ) {
            ISSUE(kt + 64, cur ^ 1);                 // prefetch next tile, stays in flight under compute
            asm volatile("s_waitcnt vmcnt(4)" ::: "memory");   // tile-kt loads complete; next-tile's 4 remain
        } else {
            asm volatile("s_waitcnt vmcnt(0)" ::: "memory");   // last tile: drain
        }
        __builtin_amdgcn_sched_barrier(0);           // rule 18: pin ds_reads below the wait

        const unsigned short* Klc = &Kl[cur][0];
        const unsigned short* Vlc = &Vl[cur][0];

        // S^T = mfma(K, Q): D[k][q], col q = lane&15, row k = kb*16 + l4*4 + r
        f32x4 sacc[2][4] = {};
        __builtin_amdgcn_s_setprio(1);
        #pragma unroll
        for (int ds = 0; ds < 2; ds++)
            #pragma unroll
            for (int kb = 0; kb < 4; kb++) {
                int krow = kb * 16 + l15;
                bf16x8 kf = *(const bf16x8*)((const char*)Klc + krow * 128 + ((ds * 64 + l4 * 16) ^ ((krow & 7) << 4)));
                sacc[0][kb] = MFMA(kf, qf[0][ds], sacc[0][kb]);
                sacc[1][kb] = MFMA(kf, qf[1][ds], sacc[1][kb]);
            }
        __builtin_amdgcn_s_setprio(0);

        // online softmax (lazy-max T13, exp2 domain), per lane: 16 k-values for q = qb*16 + l15
        #pragma unroll
        for (int qb = 0; qb < 2; qb++) {
            float pm = -1e30f;
            #pragma unroll
            for (int kb = 0; kb < 4; kb++)
                #pragma unroll
                for (int r = 0; r < 4; r++) pm = fmaxf(pm, sacc[qb][kb][r]);
            pm = fmaxf(pm, __shfl_xor(pm, 16));
            pm = fmaxf(pm, __shfl_xor(pm, 32));
            // defer-max: skip O/l rescale while tile max stays within 2^8 of running max
            bool skip = __all(pm <= mst[qb] + 8.f);
            float mnew = skip ? mst[qb] : fmaxf(mst[qb], pm);
            float ls = 0.f;
            bf16x4 pw[4];
            #pragma unroll
            for (int kb = 0; kb < 4; kb++) {
                float p0 = EXP2(sacc[qb][kb][0] - mnew);
                float p1 = EXP2(sacc[qb][kb][1] - mnew);
                float p2 = EXP2(sacc[qb][kb][2] - mnew);
                float p3 = EXP2(sacc[qb][kb][3] - mnew);
                ls += (p0 + p1) + (p2 + p3);
                pw[kb][0] = (__bf16)p0; pw[kb][1] = (__bf16)p1;   // compiler emits v_cvt_pk_bf16_f32
                pw[kb][2] = (__bf16)p2; pw[kb][3] = (__bf16)p3;
            }
            ls += __shfl_xor(ls, 16);
            ls += __shfl_xor(ls, 32);
            if (skip) {
                lst[qb] += ls;
            } else {
                float corr = EXP2(mst[qb] - mnew);
                mst[qb] = mnew;
                lst[qb] = lst[qb] * corr + ls;
                #pragma unroll
                for (int db = 0; db < 4; db++) accO[qb][db] *= corr;
            }
            int prow = wave * 32 + qb * 16 + l15;
            #pragma unroll
            for (int kb = 0; kb < 4; kb++) {
                int pbyte = prow * 128 + ((kb * 32 + l4 * 8) ^ ((prow & 7) << 4));
                *(bf16x4*)((char*)Pl + pbyte) = pw[kb];   // per-wave region: no barrier needed
            }
        }

        // O^T += mfma(V^T, P): D[d][q]
        __builtin_amdgcn_s_setprio(1);
        #pragma unroll
        for (int ds = 0; ds < 2; ds++) {
            int prow0 = wave * 32 + l15, prow1 = prow0 + 16;
            bf16x8 pf0 = *(const bf16x8*)((const char*)Pl + prow0 * 128 + ((ds * 64 + l4 * 16) ^ ((prow0 & 7) << 4)));
            bf16x8 pf1 = *(const bf16x8*)((const char*)Pl + prow1 * 128 + ((ds * 64 + l4 * 16) ^ ((prow1 & 7) << 4)));
            #pragma unroll
            for (int db = 0; db < 4; db++) {
                int vrow = db * 16 + l15;
                bf16x8 vf = *(const bf16x8*)((const char*)Vlc + vrow * 128 + ((ds * 64 + l4 * 16) ^ ((vrow & 7) << 4)));
                accO[0][db] = MFMA(vf, pf0, accO[0][db]);
                accO[1][db] = MFMA(vf, pf1, accO[1][db]);
            }
        }
        __builtin_amdgcn_s_setprio(0);
    }
#undef ISSUE

    #pragma unroll
    for (int qb = 0; qb < 2; qb++) {
        float inv = 1.f / lst[qb];
        int tok = q0 + qb * 16 + l15;
        size_t rowo = ((size_t)b * SEQ + tok) * EMBED + h * HD;
        #pragma unroll
        for (int db = 0; db < 4; db++) {
            u32x2 w = { pack2(accO[qb][db][0] * inv, accO[qb][db][1] * inv),
                        pack2(accO[qb][db][2] * inv, accO[qb][db][3] * inv) };
            *(u32x2*)(O + rowo + db * 16 + l4 * 4) = w;
        }
    }
}

// ---------------- proj GEMM: O bf16 [8192][1024] @ Wproj^T + bias -> fp32 out ----------------
__global__ __launch_bounds__(256) void k_proj(const unsigned short* __restrict__ A,
    const unsigned short* __restrict__ wt, const float* __restrict__ bias, float* __restrict__ out)
{
    __shared__ unsigned short Al[128 * 32];
    __shared__ unsigned short Bl[128 * 32];
    const int tid = threadIdx.x;
    const int wave = tid >> 6, lane = tid & 63;
    const int l15 = lane & 15, l4 = lane >> 4;
    const int wr = wave >> 1, wc = wave & 1;
    const int tm = blockIdx.y * 128, tc = blockIdx.x * 128;

    const int srow = wave * 32 + (lane >> 2);
    const int scol = (lane & 3) * 8;
    const unsigned short* ga = A  + (size_t)(tm + srow) * EMBED + scol;
    const unsigned short* gb = wt + (size_t)(tc + srow) * EMBED + scol;

    f32x4 acc[4][4] = {};
    for (int k0 = 0; k0 < EMBED; k0 += 32) {
        __syncthreads();
        __builtin_amdgcn_global_load_lds(GLB(ga + k0),              LDSP(Al + wave * 1024),       16, 0, 0);
        __builtin_amdgcn_global_load_lds(GLB(ga + k0 + 16 * EMBED), LDSP(Al + wave * 1024 + 512), 16, 0, 0);
        __builtin_amdgcn_global_load_lds(GLB(gb + k0),              LDSP(Bl + wave * 1024),       16, 0, 0);
        __builtin_amdgcn_global_load_lds(GLB(gb + k0 + 16 * EMBED), LDSP(Bl + wave * 1024 + 512), 16, 0, 0);
        __syncthreads();
        bf16x8 af[4], bfr[4];
        #pragma unroll
        for (int m = 0; m < 4; m++) af[m]  = *(const bf16x8*)&Al[(wr * 64 + m * 16 + l15) * 32 + l4 * 8];
        #pragma unroll
        for (int n = 0; n < 4; n++) bfr[n] = *(const bf16x8*)&Bl[(wc * 64 + n * 16 + l15) * 32 + l4 * 8];
        #pragma unroll
        for (int m = 0; m < 4; m++)
            #pragma unroll
            for (int n = 0; n < 4; n++)
                acc[m][n] = MFMA(af[m], bfr[n], acc[m][n]);
    }

    #pragma unroll
    for (int m = 0; m < 4; m++)
        #pragma unroll
        for (int j = 0; j < 4; j++) {
            int row = tm + wr * 64 + m * 16 + l4 * 4 + j;
            #pragma unroll
            for (int n = 0; n < 4; n++) {
                int col = tc + wc * 64 + n * 16 + l15;
                out[(size_t)row * EMBED + col] = acc[m][n][j] + bias[col];
            }
        }
}

extern "C" void kernel_launch(void* const* d_in, const int* in_sizes, int n_in,
                              void* d_out, int out_size, void* d_ws, size_t ws_size,
                              hipStream_t stream) {
    const float* x     = (const float*)d_in[0];
    const float* rc    = (const float*)d_in[1];
    const float* rs    = (const float*)d_in[2];
    const float* Wqkv  = (const float*)d_in[3];
    const float* bqkv  = (const float*)d_in[4];
    const float* Wproj = (const float*)d_in[5];
    const float* bproj = (const float*)d_in[6];
    char* ws = (char*)d_ws;
    // workspace layout (75.5 MB): xb region is reused for attention output
    unsigned short* xb  = (unsigned short*)(ws);                 // 16.78MB : x bf16, later attn-O bf16
    unsigned short* wqt = (unsigned short*)(ws + 16777216);      //  6.29MB : Wqkv^T bf16
    unsigned short* wpt = (unsigned short*)(ws + 23068672);      //  2.10MB : Wproj^T bf16
    unsigned short* Qb  = (unsigned short*)(ws + 25165824);      // 16.78MB : Q (roped, prescaled by QSCALE)
    unsigned short* Kb  = (unsigned short*)(ws + 41943040);      // 16.78MB : K (roped)
    unsigned short* Vt  = (unsigned short*)(ws + 58720256);      // 16.78MB : V^T
    float* outp = (float*)d_out;

    k_convert  <<<8192, 256, 0, stream>>>(x, xb, 2097152);
    k_transpose<<<dim3(96, 32), 256, 0, stream>>>(Wqkv, wqt, 1024, 3072);
    k_transpose<<<dim3(32, 32), 256, 0, stream>>>(Wproj, wpt, 1024, 1024);
    k_qkv      <<<dim3(24, 64), 256, 0, stream>>>(xb, wqt, bqkv, rc, rs, Qb, Kb, Vt);
    k_attn     <<<dim3(16, 64), 256, 0, stream>>>(Qb, Kb, Vt, xb);
    k_proj     <<<dim3(8, 64),  256, 0, stream>>>(xb, wpt, bproj, outp);
}

// Round 8
// 339.602 us; speedup vs baseline: 1.0073x; 1.0073x over previous
//
#include <hip/hip_runtime.h>
#include <stdint.h>

#define EMBED 1024
#define NHEAD 16
#define HD    64
#define SEQ   2048
#define BATCH 4

typedef __bf16 bf16x8 __attribute__((ext_vector_type(8)));
typedef __bf16 bf16x2t __attribute__((ext_vector_type(2)));
typedef float  f32x4  __attribute__((ext_vector_type(4)));
typedef unsigned int u32x2 __attribute__((ext_vector_type(2)));
typedef unsigned int u32x4 __attribute__((ext_vector_type(4)));

#define GLB(p)  ((__attribute__((address_space(1))) unsigned int*)(p))
#define LDSP(p) ((__attribute__((address_space(3))) unsigned int*)(p))
#define MFMA(a,b,c) __builtin_amdgcn_mfma_f32_16x16x32_bf16(a,b,c,0,0,0)
#define EXP2(x) __builtin_amdgcn_exp2f(x)

// Q pre-scale: (1/sqrt(64)) * log2(e) so attention probs are exp2(S - m) directly
#define QSCALE 0.18033688011112042f

__device__ __forceinline__ unsigned int f2bf(float f) {
    unsigned int u = __float_as_uint(f);
    return (u + 0x7FFFu + ((u >> 16) & 1u)) >> 16;   // RNE fp32->bf16
}
__device__ __forceinline__ unsigned int pack2(float a, float b) {
    return f2bf(a) | (f2bf(b) << 16);
}
__device__ __forceinline__ unsigned int cvtpk(float lo, float hi) {
    bf16x2t w; w[0] = (__bf16)lo; w[1] = (__bf16)hi;   // compiler emits v_cvt_pk_bf16_f32
    return __builtin_bit_cast(unsigned int, w);
}

// permlane swaps via BUILTINS (hazard-safe; raw inline asm bypasses the compiler's
// VALU cross-lane hazard recognizer -> sporadic wrong lanes, R6 lesson).
// perm32: new_a = [a_lo, b_lo], new_b = [a_hi, b_hi]   (32-lane halves)
// perm16: new_a = [a0, b0, a2, b2], new_b = [a1, b1, a3, b3]   (16-lane quarters)
__device__ __forceinline__ void pswap32(unsigned int &a, unsigned int &b) {
#if __has_builtin(__builtin_amdgcn_permlane32_swap)
    u32x2 r = __builtin_amdgcn_permlane32_swap(a, b, false, false);
    a = r[0]; b = r[1];
#else
    unsigned int sa = (unsigned int)__shfl_xor((int)a, 32);
    unsigned int sb = (unsigned int)__shfl_xor((int)b, 32);
    bool hi = (threadIdx.x & 32) != 0;
    unsigned int na = hi ? sb : a;
    unsigned int nb = hi ? b : sa;
    a = na; b = nb;
#endif
}
__device__ __forceinline__ void pswap16(unsigned int &a, unsigned int &b) {
#if __has_builtin(__builtin_amdgcn_permlane16_swap)
    u32x2 r = __builtin_amdgcn_permlane16_swap(a, b, false, false);
    a = r[0]; b = r[1];
#else
    unsigned int sa = (unsigned int)__shfl_xor((int)a, 16);
    unsigned int sb = (unsigned int)__shfl_xor((int)b, 16);
    bool oddq = (threadIdx.x & 16) != 0;
    unsigned int na = oddq ? sb : a;
    unsigned int nb = oddq ? b : sa;
    a = na; b = nb;
#endif
}
// quarter-exchange composite: (a,b) -> a = [aq0,aq2,bq0,bq2], b = [aq1,aq3,bq1,bq3]
__device__ __forceinline__ void pswap_q(unsigned int &a, unsigned int &b) {
    pswap32(a, b);
    pswap16(a, b);
}

// ---------------- x fp32 -> bf16 ----------------
__global__ void k_convert(const float* __restrict__ in, unsigned short* __restrict__ out, int n4) {
    int i = blockIdx.x * 256 + threadIdx.x;
    if (i >= n4) return;
    f32x4 v = ((const f32x4*)in)[i];
    u32x2 w = { pack2(v[0], v[1]), pack2(v[2], v[3]) };
    ((u32x2*)out)[i] = w;
}

// ---------------- W [K][C] fp32 -> Wt [C][K] bf16 (LDS-tiled transpose) ----------------
__global__ void k_transpose(const float* __restrict__ in, unsigned short* __restrict__ out, int K, int C) {
    __shared__ float t[32][33];
    int c0 = blockIdx.x * 32, k0 = blockIdx.y * 32;
    int tid = threadIdx.x;
    #pragma unroll
    for (int i = 0; i < 4; i++) {
        int e = tid + i * 256;
        t[e >> 5][e & 31] = in[(size_t)(k0 + (e >> 5)) * C + c0 + (e & 31)];
    }
    __syncthreads();
    #pragma unroll
    for (int i = 0; i < 4; i++) {
        int e = tid + i * 256;
        int cl = e >> 5, kl = e & 31;
        out[(size_t)(c0 + cl) * K + k0 + kl] = (unsigned short)f2bf(t[kl][cl]);
    }
}

// ---------------- QKV GEMM + bias + RoPE, writes Q,K [bh][n][64] (Q pre-scaled by QSCALE), V^T [bh][64][n] ----------------
__global__ __launch_bounds__(256) void k_qkv(const unsigned short* __restrict__ xb,
    const unsigned short* __restrict__ wt, const float* __restrict__ bias,
    const float* __restrict__ rc, const float* __restrict__ rs,
    unsigned short* __restrict__ Qb, unsigned short* __restrict__ Kb, unsigned short* __restrict__ Vt)
{
    __shared__ unsigned short Al[128 * 32];
    __shared__ unsigned short Bl[128 * 32];
    const int tid = threadIdx.x;
    const int wave = tid >> 6, lane = tid & 63;
    const int l15 = lane & 15, l4 = lane >> 4;
    const int wr = wave >> 1, wc = wave & 1;
    const int tm = blockIdx.y * 128, tc = blockIdx.x * 128;

    const int srow = wave * 32 + (lane >> 2);
    const int scol = (lane & 3) * 8;
    const unsigned short* ga = xb + (size_t)(tm + srow) * EMBED + scol;
    const unsigned short* gb = wt + (size_t)(tc + srow) * EMBED + scol;

    f32x4 acc[4][4] = {};
    for (int k0 = 0; k0 < EMBED; k0 += 32) {
        __syncthreads();
        __builtin_amdgcn_global_load_lds(GLB(ga + k0),               LDSP(Al + wave * 1024),       16, 0, 0);
        __builtin_amdgcn_global_load_lds(GLB(ga + k0 + 16 * EMBED),  LDSP(Al + wave * 1024 + 512), 16, 0, 0);
        __builtin_amdgcn_global_load_lds(GLB(gb + k0),               LDSP(Bl + wave * 1024),       16, 0, 0);
        __builtin_amdgcn_global_load_lds(GLB(gb + k0 + 16 * EMBED),  LDSP(Bl + wave * 1024 + 512), 16, 0, 0);
        __syncthreads();
        bf16x8 af[4], bfr[4];
        #pragma unroll
        for (int m = 0; m < 4; m++) af[m]  = *(const bf16x8*)&Al[(wr * 64 + m * 16 + l15) * 32 + l4 * 8];
        #pragma unroll
        for (int n = 0; n < 4; n++) bfr[n] = *(const bf16x8*)&Bl[(wc * 64 + n * 16 + l15) * 32 + l4 * 8];
        #pragma unroll
        for (int m = 0; m < 4; m++)
            #pragma unroll
            for (int n = 0; n < 4; n++)
                acc[m][n] = MFMA(af[m], bfr[n], acc[m][n]);
    }

    const int cb = tc + wc * 64;          // wave col base; one head per wave
    const int s = cb >> 10;               // 0=q 1=k 2=v
    const int h = (cb >> 6) & 15;
    if (s < 2) {
        #pragma unroll
        for (int m = 0; m < 4; m++)
            #pragma unroll
            for (int j = 0; j < 4; j++) {
                int row = tm + wr * 64 + m * 16 + l4 * 4 + j;
                int b = row >> 11, pos = row & (SEQ - 1);
                float v[4];
                #pragma unroll
                for (int n = 0; n < 4; n++) v[n] = acc[m][n][j] + bias[cb + n * 16 + l15];
                float o[4];
                #pragma unroll
                for (int p = 0; p < 2; p++) {
                    int d1 = p * 16 + l15;
                    float c1 = rc[pos * HD + d1],      s1 = rs[pos * HD + d1];
                    float c2 = rc[pos * HD + d1 + 32], s2 = rs[pos * HD + d1 + 32];
                    o[p]     = v[p] * c1     - v[p + 2] * s1;   // d < 32 : q*cos - q[d+32]*sin
                    o[p + 2] = v[p + 2] * c2 + v[p] * s2;       // d >= 32: q*cos + q[d-32]*sin
                }
                float mul = (s == 0) ? QSCALE : 1.0f;           // fold 1/sqrt(64)*log2e into Q
                unsigned short* dst = (s == 0 ? Qb : Kb) + ((size_t)(b * NHEAD + h) * SEQ + pos) * HD;
                #pragma unroll
                for (int n = 0; n < 4; n++) dst[n * 16 + l15] = (unsigned short)f2bf(o[n] * mul);
            }
    } else {
        #pragma unroll
        for (int m = 0; m < 4; m++) {
            int row0 = tm + wr * 64 + m * 16 + l4 * 4;
            int b = row0 >> 11, pos0 = row0 & (SEQ - 1);
            #pragma unroll
            for (int n = 0; n < 4; n++) {
                float bb = bias[cb + n * 16 + l15];
                u32x2 w = { pack2(acc[m][n][0] + bb, acc[m][n][1] + bb),
                            pack2(acc[m][n][2] + bb, acc[m][n][3] + bb) };
                *(u32x2*)(Vt + ((size_t)(b * NHEAD + h) * HD + n * 16 + l15) * SEQ + pos0) = w;
            }
        }
    }
}

// ---------------- flash attention: Q,K [bh][n][64] (Q pre-scaled), V^T [bh][64][n] -> O [b*n][h*64+d] bf16 ----------------
// Double-buffered K/V staging, race-free 1-barrier/tile (wait-own-loads THEN barrier), in-register P (T12, builtins).
__global__ __launch_bounds__(256) void k_attn(const unsigned short* __restrict__ Qb,
    const unsigned short* __restrict__ Kb, const unsigned short* __restrict__ Vt,
    unsigned short* __restrict__ O)
{
    __shared__ unsigned short Kl[2][64 * 64];   // [buf][k][d], XOR-swizzled rows (128B)
    __shared__ unsigned short Vl[2][64 * 64];   // [buf][d][tok], XOR-swizzled
    const int tid = threadIdx.x, wave = tid >> 6, lane = tid & 63;
    const int l15 = lane & 15, l4 = lane >> 4;
    const int bh = blockIdx.y;
    const int b = bh >> 4, h = bh & 15;
    const int q0 = blockIdx.x * 128 + wave * 32;

    // Q fragments in registers (B-operand: lane&15 = q row, walks d)
    const unsigned short* Qg = Qb + ((size_t)bh * SEQ + q0) * HD;
    bf16x8 qf[2][2];
    #pragma unroll
    for (int qb = 0; qb < 2; qb++)
        #pragma unroll
        for (int ds = 0; ds < 2; ds++)
            qf[qb][ds] = *(const bf16x8*)(Qg + (qb * 16 + l15) * HD + ds * 32 + l4 * 8);

    // staging: pre-swizzled global source so linear global_load_lds yields swizzled LDS (rule 21)
    const int srow = lane >> 3;                       // 0..7
    const int selem = ((lane & 7) * 8) ^ ((srow & 7) * 8);
    const unsigned short* kg = Kb + (size_t)bh * SEQ * HD + (size_t)(wave * 16 + srow) * HD + selem;
    const unsigned short* vg = Vt + (size_t)bh * HD * SEQ + (size_t)(wave * 16 + srow) * SEQ + selem;

#define ISSUE(kt_, bi_) do { \
    __builtin_amdgcn_global_load_lds(GLB(kg + (size_t)(kt_) * HD),       LDSP(&Kl[bi_][0] + wave * 1024),       16, 0, 0); \
    __builtin_amdgcn_global_load_lds(GLB(kg + (size_t)((kt_) + 8) * HD), LDSP(&Kl[bi_][0] + wave * 1024 + 512), 16, 0, 0); \
    __builtin_amdgcn_global_load_lds(GLB(vg + (kt_)),                    LDSP(&Vl[bi_][0] + wave * 1024),       16, 0, 0); \
    __builtin_amdgcn_global_load_lds(GLB(vg + 8 * SEQ + (kt_)),          LDSP(&Vl[bi_][0] + wave * 1024 + 512), 16, 0, 0); \
} while (0)

    f32x4 accO[2][4] = {};
    float mst[2] = { -1e30f, -1e30f }, lst[2] = { 0.f, 0.f };

    ISSUE(0, 0);                                     // prologue: tile 0 in flight

    for (int kt = 0; kt < SEQ; kt += 64) {
        const int cur = (kt >> 6) & 1;
        // own tile-kt loads landed, THEN barrier => all waves' tile-kt loads landed
        // and all waves are done reading buf[cur^1] (their tile kt-64 compute precedes this barrier).
        asm volatile("s_waitcnt vmcnt(0)" ::: "memory");
        __builtin_amdgcn_s_barrier();
        if (kt + 64 < SEQ) ISSUE(kt + 64, cur ^ 1);  // in flight under compute(kt); lands before next iter's wait
        __builtin_amdgcn_sched_barrier(0);           // rule 18: pin ds_reads below the wait/barrier

        const unsigned short* Klc = &Kl[cur][0];
        const unsigned short* Vlc = &Vl[cur][0];

        // S^T = mfma(K, Q): D[k][q], col q = lane&15, row k = kb*16 + l4*4 + r
        f32x4 sacc[2][4] = {};
        __builtin_amdgcn_s_setprio(1);
        #pragma unroll
        for (int ds = 0; ds < 2; ds++)
            #pragma unroll
            for (int kb = 0; kb < 4; kb++) {
                int krow = kb * 16 + l15;
                bf16x8 kf = *(const bf16x8*)((const char*)Klc + krow * 128 + ((ds * 64 + l4 * 16) ^ ((krow & 7) << 4)));
                sacc[0][kb] = MFMA(kf, qf[0][ds], sacc[0][kb]);
                sacc[1][kb] = MFMA(kf, qf[1][ds], sacc[1][kb]);
            }
        __builtin_amdgcn_s_setprio(0);

        // online softmax (lazy-max T13, exp2 domain) + in-register P transpose (T12)
        bf16x8 pf[2][2];
        #pragma unroll
        for (int qb = 0; qb < 2; qb++) {
            float pm = -1e30f;
            #pragma unroll
            for (int kb = 0; kb < 4; kb++)
                #pragma unroll
                for (int r = 0; r < 4; r++) pm = fmaxf(pm, sacc[qb][kb][r]);
            pm = fmaxf(pm, __shfl_xor(pm, 16));      // proven R2-R4 reduce path
            pm = fmaxf(pm, __shfl_xor(pm, 32));
            // defer-max: skip O/l rescale while tile max stays within 2^8 of running max
            bool skip = __all(pm <= mst[qb] + 8.f);
            float mnew = skip ? mst[qb] : fmaxf(mst[qb], pm);
            float ls = 0.f;
            unsigned int w[4][2];
            #pragma unroll
            for (int kb = 0; kb < 4; kb++) {
                float p0 = EXP2(sacc[qb][kb][0] - mnew);
                float p1 = EXP2(sacc[qb][kb][1] - mnew);
                float p2 = EXP2(sacc[qb][kb][2] - mnew);
                float p3 = EXP2(sacc[qb][kb][3] - mnew);
                ls += (p0 + p1) + (p2 + p3);
                w[kb][0] = cvtpk(p0, p1);
                w[kb][1] = cvtpk(p2, p3);
            }
            ls += __shfl_xor(ls, 16);
            ls += __shfl_xor(ls, 32);
            if (skip) {
                lst[qb] += ls;
            } else {
                float corr = EXP2(mst[qb] - mnew);
                mst[qb] = mnew;
                lst[qb] = lst[qb] * corr + ls;
                #pragma unroll
                for (int db = 0; db < 4; db++) accO[qb][db] *= corr;
            }
            // lane(q,l4) holds w[kb][t] = P[k=kb*16+l4*4+2t..+1][q]; quarter-swaps
            // redistribute into PV B-fragments: pf[ds] word m at quarter g' = P[k=ds*32+8g'+2m..+1][q].
            pswap_q(w[0][0], w[1][0]);   // -> pf0 word0, word2
            pswap_q(w[0][1], w[1][1]);   // -> pf0 word1, word3
            pswap_q(w[2][0], w[3][0]);   // -> pf1 word0, word2
            pswap_q(w[2][1], w[3][1]);   // -> pf1 word1, word3
            u32x4 f0 = { w[0][0], w[0][1], w[1][0], w[1][1] };
            u32x4 f1 = { w[2][0], w[2][1], w[3][0], w[3][1] };
            pf[qb][0] = __builtin_bit_cast(bf16x8, f0);
            pf[qb][1] = __builtin_bit_cast(bf16x8, f1);
        }

        // O^T += mfma(V^T, P): D[d][q]
        __builtin_amdgcn_s_setprio(1);
        #pragma unroll
        for (int ds = 0; ds < 2; ds++)
            #pragma unroll
            for (int db = 0; db < 4; db++) {
                int vrow = db * 16 + l15;
                bf16x8 vf = *(const bf16x8*)((const char*)Vlc + vrow * 128 + ((ds * 64 + l4 * 16) ^ ((vrow & 7) << 4)));
                accO[0][db] = MFMA(vf, pf[0][ds], accO[0][db]);
                accO[1][db] = MFMA(vf, pf[1][ds], accO[1][db]);
            }
        __builtin_amdgcn_s_setprio(0);
    }
#undef ISSUE

    #pragma unroll
    for (int qb = 0; qb < 2; qb++) {
        float inv = 1.f / lst[qb];
        int tok = q0 + qb * 16 + l15;
        size_t rowo = ((size_t)b * SEQ + tok) * EMBED + h * HD;
        #pragma unroll
        for (int db = 0; db < 4; db++) {
            u32x2 w = { pack2(accO[qb][db][0] * inv, accO[qb][db][1] * inv),
                        pack2(accO[qb][db][2] * inv, accO[qb][db][3] * inv) };
            *(u32x2*)(O + rowo + db * 16 + l4 * 4) = w;
        }
    }
}

// ---------------- proj GEMM: O bf16 [8192][1024] @ Wproj^T + bias -> fp32 out ----------------
__global__ __launch_bounds__(256) void k_proj(const unsigned short* __restrict__ A,
    const unsigned short* __restrict__ wt, const float* __restrict__ bias, float* __restrict__ out)
{
    __shared__ unsigned short Al[128 * 32];
    __shared__ unsigned short Bl[128 * 32];
    const int tid = threadIdx.x;
    const int wave = tid >> 6, lane = tid & 63;
    const int l15 = lane & 15, l4 = lane >> 4;
    const int wr = wave >> 1, wc = wave & 1;
    const int tm = blockIdx.y * 128, tc = blockIdx.x * 128;

    const int srow = wave * 32 + (lane >> 2);
    const int scol = (lane & 3) * 8;
    const unsigned short* ga = A  + (size_t)(tm + srow) * EMBED + scol;
    const unsigned short* gb = wt + (size_t)(tc + srow) * EMBED + scol;

    f32x4 acc[4][4] = {};
    for (int k0 = 0; k0 < EMBED; k0 += 32) {
        __syncthreads();
        __builtin_amdgcn_global_load_lds(GLB(ga + k0),              LDSP(Al + wave * 1024),       16, 0, 0);
        __builtin_amdgcn_global_load_lds(GLB(ga + k0 + 16 * EMBED), LDSP(Al + wave * 1024 + 512), 16, 0, 0);
        __builtin_amdgcn_global_load_lds(GLB(gb + k0),              LDSP(Bl + wave * 1024),       16, 0, 0);
        __builtin_amdgcn_global_load_lds(GLB(gb + k0 + 16 * EMBED), LDSP(Bl + wave * 1024 + 512), 16, 0, 0);
        __syncthreads();
        bf16x8 af[4], bfr[4];
        #pragma unroll
        for (int m = 0; m < 4; m++) af[m]  = *(const bf16x8*)&Al[(wr * 64 + m * 16 + l15) * 32 + l4 * 8];
        #pragma unroll
        for (int n = 0; n < 4; n++) bfr[n] = *(const bf16x8*)&Bl[(wc * 64 + n * 16 + l15) * 32 + l4 * 8];
        #pragma unroll
        for (int m = 0; m < 4; m++)
            #pragma unroll
            for (int n = 0; n < 4; n++)
                acc[m][n] = MFMA(af[m], bfr[n], acc[m][n]);
    }

    #pragma unroll
    for (int m = 0; m < 4; m++)
        #pragma unroll
        for (int j = 0; j < 4; j++) {
            int row = tm + wr * 64 + m * 16 + l4 * 4 + j;
            #pragma unroll
            for (int n = 0; n < 4; n++) {
                int col = tc + wc * 64 + n * 16 + l15;
                out[(size_t)row * EMBED + col] = acc[m][n][j] + bias[col];
            }
        }
}

extern "C" void kernel_launch(void* const* d_in, const int* in_sizes, int n_in,
                              void* d_out, int out_size, void* d_ws, size_t ws_size,
                              hipStream_t stream) {
    const float* x     = (const float*)d_in[0];
    const float* rc    = (const float*)d_in[1];
    const float* rs    = (const float*)d_in[2];
    const float* Wqkv  = (const float*)d_in[3];
    const float* bqkv  = (const float*)d_in[4];
    const float* Wproj = (const float*)d_in[5];
    const float* bproj = (const float*)d_in[6];
    char* ws = (char*)d_ws;
    // workspace layout (75.5 MB): xb region is reused for attention output
    unsigned short* xb  = (unsigned short*)(ws);                 // 16.78MB : x bf16, later attn-O bf16
    unsigned short* wqt = (unsigned short*)(ws + 16777216);      //  6.29MB : Wqkv^T bf16
    unsigned short* wpt = (unsigned short*)(ws + 23068672);      //  2.10MB : Wproj^T bf16
    unsigned short* Qb  = (unsigned short*)(ws + 25165824);      // 16.78MB : Q (roped, prescaled by QSCALE)
    unsigned short* Kb  = (unsigned short*)(ws + 41943040);      // 16.78MB : K (roped)
    unsigned short* Vt  = (unsigned short*)(ws + 58720256);      // 16.78MB : V^T
    float* outp = (float*)d_out;

    k_convert  <<<8192, 256, 0, stream>>>(x, xb, 2097152);
    k_transpose<<<dim3(96, 32), 256, 0, stream>>>(Wqkv, wqt, 1024, 3072);
    k_transpose<<<dim3(32, 32), 256, 0, stream>>>(Wproj, wpt, 1024, 1024);
    k_qkv      <<<dim3(24, 64), 256, 0, stream>>>(xb, wqt, bqkv, rc, rs, Qb, Kb, Vt);
    k_attn     <<<dim3(16, 64), 256, 0, stream>>>(Qb, Kb, Vt, xb);
    k_proj     <<<dim3(8, 64),  256, 0, stream>>>(xb, wpt, bproj, outp);
}

// Round 9
// 329.930 us; speedup vs baseline: 1.0368x; 1.0293x over previous
//
#include <hip/hip_runtime.h>
#include <stdint.h>

#define EMBED 1024
#define NHEAD 16
#define HD    64
#define SEQ   2048
#define BATCH 4

typedef __bf16 bf16x8 __attribute__((ext_vector_type(8)));
typedef __bf16 bf16x2t __attribute__((ext_vector_type(2)));
typedef float  f32x4  __attribute__((ext_vector_type(4)));
typedef unsigned int u32x2 __attribute__((ext_vector_type(2)));
typedef unsigned int u32x4 __attribute__((ext_vector_type(4)));

#define GLB(p)  ((__attribute__((address_space(1))) unsigned int*)(p))
#define LDSP(p) ((__attribute__((address_space(3))) unsigned int*)(p))
#define MFMA(a,b,c) __builtin_amdgcn_mfma_f32_16x16x32_bf16(a,b,c,0,0,0)
#define EXP2(x) __builtin_amdgcn_exp2f(x)
#define F3(a,b,c) fmaxf(fmaxf((a),(b)),(c))   // clang fuses to v_max3_f32

// Q pre-scale: (1/sqrt(64)) * log2(e) so attention probs are exp2(S - m) directly
#define QSCALE 0.18033688011112042f

__device__ __forceinline__ unsigned int f2bf(float f) {
    unsigned int u = __float_as_uint(f);
    return (u + 0x7FFFu + ((u >> 16) & 1u)) >> 16;   // RNE fp32->bf16
}
__device__ __forceinline__ unsigned int pack2(float a, float b) {
    return f2bf(a) | (f2bf(b) << 16);
}
__device__ __forceinline__ unsigned int cvtpk(float lo, float hi) {
    bf16x2t w; w[0] = (__bf16)lo; w[1] = (__bf16)hi;   // compiler emits v_cvt_pk_bf16_f32
    return __builtin_bit_cast(unsigned int, w);
}

// permlane swaps via BUILTINS (hazard-safe; proven on HW in R8).
__device__ __forceinline__ void pswap32(unsigned int &a, unsigned int &b) {
#if __has_builtin(__builtin_amdgcn_permlane32_swap)
    u32x2 r = __builtin_amdgcn_permlane32_swap(a, b, false, false);
    a = r[0]; b = r[1];
#else
    unsigned int sa = (unsigned int)__shfl_xor((int)a, 32);
    unsigned int sb = (unsigned int)__shfl_xor((int)b, 32);
    bool hi = (threadIdx.x & 32) != 0;
    unsigned int na = hi ? sb : a;
    unsigned int nb = hi ? b : sa;
    a = na; b = nb;
#endif
}
__device__ __forceinline__ void pswap16(unsigned int &a, unsigned int &b) {
#if __has_builtin(__builtin_amdgcn_permlane16_swap)
    u32x2 r = __builtin_amdgcn_permlane16_swap(a, b, false, false);
    a = r[0]; b = r[1];
#else
    unsigned int sa = (unsigned int)__shfl_xor((int)a, 16);
    unsigned int sb = (unsigned int)__shfl_xor((int)b, 16);
    bool oddq = (threadIdx.x & 16) != 0;
    unsigned int na = oddq ? sb : a;
    unsigned int nb = oddq ? b : sa;
    a = na; b = nb;
#endif
}
// quarter-exchange composite: (a,b) -> a = [aq0,aq2,bq0,bq2], b = [aq1,aq3,bq1,bq3]
__device__ __forceinline__ void pswap_q(unsigned int &a, unsigned int &b) {
    pswap32(a, b);
    pswap16(a, b);
}
// reduce across the 4 16-lane quarters (same lane&15) on the VALU — replaces
// 2 ds_swizzle shuffles (~240 serial cycles) with ~4 VALU ops (R8 lesson:
// the serial softmax chain, not pipe throughput, sets attn wall time).
__device__ __forceinline__ float red_max4(float x) {
    unsigned int a = __float_as_uint(x), b = a;
    pswap32(a, b);
    float y = fmaxf(__uint_as_float(a), __uint_as_float(b));
    unsigned int c = __float_as_uint(y), d = c;
    pswap16(c, d);
    return fmaxf(__uint_as_float(c), __uint_as_float(d));
}
__device__ __forceinline__ float red_sum4(float x) {
    unsigned int a = __float_as_uint(x), b = a;
    pswap32(a, b);
    float y = __uint_as_float(a) + __uint_as_float(b);
    unsigned int c = __float_as_uint(y), d = c;
    pswap16(c, d);
    return __uint_as_float(c) + __uint_as_float(d);
}

// ---------------- x fp32 -> bf16 ----------------
__global__ void k_convert(const float* __restrict__ in, unsigned short* __restrict__ out, int n4) {
    int i = blockIdx.x * 256 + threadIdx.x;
    if (i >= n4) return;
    f32x4 v = ((const f32x4*)in)[i];
    u32x2 w = { pack2(v[0], v[1]), pack2(v[2], v[3]) };
    ((u32x2*)out)[i] = w;
}

// ---------------- W [K][C] fp32 -> Wt [C][K] bf16 (LDS-tiled transpose) ----------------
__global__ void k_transpose(const float* __restrict__ in, unsigned short* __restrict__ out, int K, int C) {
    __shared__ float t[32][33];
    int c0 = blockIdx.x * 32, k0 = blockIdx.y * 32;
    int tid = threadIdx.x;
    #pragma unroll
    for (int i = 0; i < 4; i++) {
        int e = tid + i * 256;
        t[e >> 5][e & 31] = in[(size_t)(k0 + (e >> 5)) * C + c0 + (e & 31)];
    }
    __syncthreads();
    #pragma unroll
    for (int i = 0; i < 4; i++) {
        int e = tid + i * 256;
        int cl = e >> 5, kl = e & 31;
        out[(size_t)(c0 + cl) * K + k0 + kl] = (unsigned short)f2bf(t[kl][cl]);
    }
}

// ---------------- QKV GEMM + bias + RoPE, double-buffered 1-barrier K-loop (R8 attn pattern) ----------------
__global__ __launch_bounds__(256) void k_qkv(const unsigned short* __restrict__ xb,
    const unsigned short* __restrict__ wt, const float* __restrict__ bias,
    const float* __restrict__ rc, const float* __restrict__ rs,
    unsigned short* __restrict__ Qb, unsigned short* __restrict__ Kb, unsigned short* __restrict__ Vt)
{
    __shared__ unsigned short Al[2][128 * 32];
    __shared__ unsigned short Bl[2][128 * 32];
    const int tid = threadIdx.x;
    const int wave = tid >> 6, lane = tid & 63;
    const int l15 = lane & 15, l4 = lane >> 4;
    const int wr = wave >> 1, wc = wave & 1;
    const int tm = blockIdx.y * 128, tc = blockIdx.x * 128;

    const int srow = wave * 32 + (lane >> 2);
    const int scol = (lane & 3) * 8;
    const unsigned short* ga = xb + (size_t)(tm + srow) * EMBED + scol;
    const unsigned short* gb = wt + (size_t)(tc + srow) * EMBED + scol;

#define GISSUE(k0_, bi_) do { \
    __builtin_amdgcn_global_load_lds(GLB(ga + (k0_)),              LDSP(&Al[bi_][0] + wave * 1024),       16, 0, 0); \
    __builtin_amdgcn_global_load_lds(GLB(ga + (k0_) + 16 * EMBED), LDSP(&Al[bi_][0] + wave * 1024 + 512), 16, 0, 0); \
    __builtin_amdgcn_global_load_lds(GLB(gb + (k0_)),              LDSP(&Bl[bi_][0] + wave * 1024),       16, 0, 0); \
    __builtin_amdgcn_global_load_lds(GLB(gb + (k0_) + 16 * EMBED), LDSP(&Bl[bi_][0] + wave * 1024 + 512), 16, 0, 0); \
} while (0)

    f32x4 acc[4][4] = {};
    GISSUE(0, 0);
    for (int k0 = 0; k0 < EMBED; k0 += 32) {
        const int cur = (k0 >> 5) & 1;
        asm volatile("s_waitcnt vmcnt(0)" ::: "memory");  // own tile-k0 loads landed
        __builtin_amdgcn_s_barrier();                     // => all waves' landed + prev compute done
        if (k0 + 32 < EMBED) GISSUE(k0 + 32, cur ^ 1);    // prefetch under compute
        __builtin_amdgcn_sched_barrier(0);
        const unsigned short* Ac = &Al[cur][0];
        const unsigned short* Bc = &Bl[cur][0];
        bf16x8 af[4], bfr[4];
        #pragma unroll
        for (int m = 0; m < 4; m++) af[m]  = *(const bf16x8*)&Ac[(wr * 64 + m * 16 + l15) * 32 + l4 * 8];
        #pragma unroll
        for (int n = 0; n < 4; n++) bfr[n] = *(const bf16x8*)&Bc[(wc * 64 + n * 16 + l15) * 32 + l4 * 8];
        #pragma unroll
        for (int m = 0; m < 4; m++)
            #pragma unroll
            for (int n = 0; n < 4; n++)
                acc[m][n] = MFMA(af[m], bfr[n], acc[m][n]);
    }
#undef GISSUE

    const int cb = tc + wc * 64;          // wave col base; one head per wave
    const int s = cb >> 10;               // 0=q 1=k 2=v
    const int h = (cb >> 6) & 15;
    if (s < 2) {
        #pragma unroll
        for (int m = 0; m < 4; m++)
            #pragma unroll
            for (int j = 0; j < 4; j++) {
                int row = tm + wr * 64 + m * 16 + l4 * 4 + j;
                int b = row >> 11, pos = row & (SEQ - 1);
                float v[4];
                #pragma unroll
                for (int n = 0; n < 4; n++) v[n] = acc[m][n][j] + bias[cb + n * 16 + l15];
                float o[4];
                #pragma unroll
                for (int p = 0; p < 2; p++) {
                    int d1 = p * 16 + l15;
                    float c1 = rc[pos * HD + d1],      s1 = rs[pos * HD + d1];
                    float c2 = rc[pos * HD + d1 + 32], s2 = rs[pos * HD + d1 + 32];
                    o[p]     = v[p] * c1     - v[p + 2] * s1;   // d < 32 : q*cos - q[d+32]*sin
                    o[p + 2] = v[p + 2] * c2 + v[p] * s2;       // d >= 32: q*cos + q[d-32]*sin
                }
                float mul = (s == 0) ? QSCALE : 1.0f;           // fold 1/sqrt(64)*log2e into Q
                unsigned short* dst = (s == 0 ? Qb : Kb) + ((size_t)(b * NHEAD + h) * SEQ + pos) * HD;
                #pragma unroll
                for (int n = 0; n < 4; n++) dst[n * 16 + l15] = (unsigned short)f2bf(o[n] * mul);
            }
    } else {
        #pragma unroll
        for (int m = 0; m < 4; m++) {
            int row0 = tm + wr * 64 + m * 16 + l4 * 4;
            int b = row0 >> 11, pos0 = row0 & (SEQ - 1);
            #pragma unroll
            for (int n = 0; n < 4; n++) {
                float bb = bias[cb + n * 16 + l15];
                u32x2 w = { pack2(acc[m][n][0] + bb, acc[m][n][1] + bb),
                            pack2(acc[m][n][2] + bb, acc[m][n][3] + bb) };
                *(u32x2*)(Vt + ((size_t)(b * NHEAD + h) * HD + n * 16 + l15) * SEQ + pos0) = w;
            }
        }
    }
}

// ---------------- flash attention: Q,K [bh][n][64] (Q pre-scaled), V^T [bh][64][n] -> O [b*n][h*64+d] bf16 ----------------
// Double-buffered K/V, 1 barrier/tile, in-register P (T12), VALU permlane reduces + max3 tree (short chain).
__global__ __launch_bounds__(256) void k_attn(const unsigned short* __restrict__ Qb,
    const unsigned short* __restrict__ Kb, const unsigned short* __restrict__ Vt,
    unsigned short* __restrict__ O)
{
    __shared__ unsigned short Kl[2][64 * 64];   // [buf][k][d], XOR-swizzled rows (128B)
    __shared__ unsigned short Vl[2][64 * 64];   // [buf][d][tok], XOR-swizzled
    const int tid = threadIdx.x, wave = tid >> 6, lane = tid & 63;
    const int l15 = lane & 15, l4 = lane >> 4;
    const int bh = blockIdx.y;
    const int b = bh >> 4, h = bh & 15;
    const int q0 = blockIdx.x * 128 + wave * 32;

    // Q fragments in registers (B-operand: lane&15 = q row, walks d)
    const unsigned short* Qg = Qb + ((size_t)bh * SEQ + q0) * HD;
    bf16x8 qf[2][2];
    #pragma unroll
    for (int qb = 0; qb < 2; qb++)
        #pragma unroll
        for (int ds = 0; ds < 2; ds++)
            qf[qb][ds] = *(const bf16x8*)(Qg + (qb * 16 + l15) * HD + ds * 32 + l4 * 8);

    // staging: pre-swizzled global source so linear global_load_lds yields swizzled LDS (rule 21)
    const int srow = lane >> 3;                       // 0..7
    const int selem = ((lane & 7) * 8) ^ ((srow & 7) * 8);
    const unsigned short* kg = Kb + (size_t)bh * SEQ * HD + (size_t)(wave * 16 + srow) * HD + selem;
    const unsigned short* vg = Vt + (size_t)bh * HD * SEQ + (size_t)(wave * 16 + srow) * SEQ + selem;

#define ISSUE(kt_, bi_) do { \
    __builtin_amdgcn_global_load_lds(GLB(kg + (size_t)(kt_) * HD),       LDSP(&Kl[bi_][0] + wave * 1024),       16, 0, 0); \
    __builtin_amdgcn_global_load_lds(GLB(kg + (size_t)((kt_) + 8) * HD), LDSP(&Kl[bi_][0] + wave * 1024 + 512), 16, 0, 0); \
    __builtin_amdgcn_global_load_lds(GLB(vg + (kt_)),                    LDSP(&Vl[bi_][0] + wave * 1024),       16, 0, 0); \
    __builtin_amdgcn_global_load_lds(GLB(vg + 8 * SEQ + (kt_)),          LDSP(&Vl[bi_][0] + wave * 1024 + 512), 16, 0, 0); \
} while (0)

    f32x4 accO[2][4] = {};
    float mst[2] = { -1e30f, -1e30f }, lst[2] = { 0.f, 0.f };

    ISSUE(0, 0);                                     // prologue: tile 0 in flight

    for (int kt = 0; kt < SEQ; kt += 64) {
        const int cur = (kt >> 6) & 1;
        asm volatile("s_waitcnt vmcnt(0)" ::: "memory");
        __builtin_amdgcn_s_barrier();
        if (kt + 64 < SEQ) ISSUE(kt + 64, cur ^ 1);
        __builtin_amdgcn_sched_barrier(0);

        const unsigned short* Klc = &Kl[cur][0];
        const unsigned short* Vlc = &Vl[cur][0];

        // S^T = mfma(K, Q): D[k][q], col q = lane&15, row k = kb*16 + l4*4 + r
        f32x4 sacc[2][4] = {};
        __builtin_amdgcn_s_setprio(1);
        #pragma unroll
        for (int ds = 0; ds < 2; ds++)
            #pragma unroll
            for (int kb = 0; kb < 4; kb++) {
                int krow = kb * 16 + l15;
                bf16x8 kf = *(const bf16x8*)((const char*)Klc + krow * 128 + ((ds * 64 + l4 * 16) ^ ((krow & 7) << 4)));
                sacc[0][kb] = MFMA(kf, qf[0][ds], sacc[0][kb]);
                sacc[1][kb] = MFMA(kf, qf[1][ds], sacc[1][kb]);
            }
        __builtin_amdgcn_s_setprio(0);

        // online softmax (lazy-max T13, exp2 domain) + in-register P transpose (T12)
        bf16x8 pf[2][2];
        #pragma unroll
        for (int qb = 0; qb < 2; qb++) {
            // max over 16 lane-local values: max3 tree, depth 3 (was 15-deep chain)
            float pm;
            {
                f32x4 s0 = sacc[qb][0], s1 = sacc[qb][1], s2 = sacc[qb][2], s3 = sacc[qb][3];
                float t0 = F3(s0[0], s0[1], s0[2]);
                float t1 = F3(s0[3], s1[0], s1[1]);
                float t2 = F3(s1[2], s1[3], s2[0]);
                float t3 = F3(s2[1], s2[2], s2[3]);
                float t4 = F3(s3[0], s3[1], s3[2]);
                pm = fmaxf(F3(t0, t1, t2), F3(t3, t4, s3[3]));
            }
            pm = red_max4(pm);                        // VALU permlane reduce (no DS latency)
            // defer-max: skip O/l rescale while tile max stays within 2^8 of running max
            bool skip = __all(pm <= mst[qb] + 8.f);
            float mnew = skip ? mst[qb] : fmaxf(mst[qb], pm);
            float sk[4];
            unsigned int w[4][2];
            #pragma unroll
            for (int kb = 0; kb < 4; kb++) {
                float p0 = EXP2(sacc[qb][kb][0] - mnew);
                float p1 = EXP2(sacc[qb][kb][1] - mnew);
                float p2 = EXP2(sacc[qb][kb][2] - mnew);
                float p3 = EXP2(sacc[qb][kb][3] - mnew);
                sk[kb] = (p0 + p1) + (p2 + p3);
                w[kb][0] = cvtpk(p0, p1);
                w[kb][1] = cvtpk(p2, p3);
            }
            float ls = (sk[0] + sk[1]) + (sk[2] + sk[3]);
            ls = red_sum4(ls);                        // VALU permlane reduce
            if (skip) {
                lst[qb] += ls;
            } else {
                float corr = EXP2(mst[qb] - mnew);
                mst[qb] = mnew;
                lst[qb] = lst[qb] * corr + ls;
                #pragma unroll
                for (int db = 0; db < 4; db++) accO[qb][db] *= corr;
            }
            // lane(q,l4) holds w[kb][t] = P[k=kb*16+l4*4+2t..+1][q]; quarter-swaps
            // redistribute into PV B-fragments: pf[ds] word m at quarter g' = P[k=ds*32+8g'+2m..+1][q].
            pswap_q(w[0][0], w[1][0]);   // -> pf0 word0, word2
            pswap_q(w[0][1], w[1][1]);   // -> pf0 word1, word3
            pswap_q(w[2][0], w[3][0]);   // -> pf1 word0, word2
            pswap_q(w[2][1], w[3][1]);   // -> pf1 word1, word3
            u32x4 f0 = { w[0][0], w[0][1], w[1][0], w[1][1] };
            u32x4 f1 = { w[2][0], w[2][1], w[3][0], w[3][1] };
            pf[qb][0] = __builtin_bit_cast(bf16x8, f0);
            pf[qb][1] = __builtin_bit_cast(bf16x8, f1);
        }

        // O^T += mfma(V^T, P): D[d][q]
        __builtin_amdgcn_s_setprio(1);
        #pragma unroll
        for (int ds = 0; ds < 2; ds++)
            #pragma unroll
            for (int db = 0; db < 4; db++) {
                int vrow = db * 16 + l15;
                bf16x8 vf = *(const bf16x8*)((const char*)Vlc + vrow * 128 + ((ds * 64 + l4 * 16) ^ ((vrow & 7) << 4)));
                accO[0][db] = MFMA(vf, pf[0][ds], accO[0][db]);
                accO[1][db] = MFMA(vf, pf[1][ds], accO[1][db]);
            }
        __builtin_amdgcn_s_setprio(0);
    }
#undef ISSUE

    #pragma unroll
    for (int qb = 0; qb < 2; qb++) {
        float inv = 1.f / lst[qb];
        int tok = q0 + qb * 16 + l15;
        size_t rowo = ((size_t)b * SEQ + tok) * EMBED + h * HD;
        #pragma unroll
        for (int db = 0; db < 4; db++) {
            u32x2 w = { pack2(accO[qb][db][0] * inv, accO[qb][db][1] * inv),
                        pack2(accO[qb][db][2] * inv, accO[qb][db][3] * inv) };
            *(u32x2*)(O + rowo + db * 16 + l4 * 4) = w;
        }
    }
}

// ---------------- proj GEMM: O bf16 [8192][1024] @ Wproj^T + bias -> fp32 out (dbuf 1-barrier) ----------------
__global__ __launch_bounds__(256) void k_proj(const unsigned short* __restrict__ A,
    const unsigned short* __restrict__ wt, const float* __restrict__ bias, float* __restrict__ out)
{
    __shared__ unsigned short Al[2][128 * 32];
    __shared__ unsigned short Bl[2][128 * 32];
    const int tid = threadIdx.x;
    const int wave = tid >> 6, lane = tid & 63;
    const int l15 = lane & 15, l4 = lane >> 4;
    const int wr = wave >> 1, wc = wave & 1;
    const int tm = blockIdx.y * 128, tc = blockIdx.x * 128;

    const int srow = wave * 32 + (lane >> 2);
    const int scol = (lane & 3) * 8;
    const unsigned short* ga = A  + (size_t)(tm + srow) * EMBED + scol;
    const unsigned short* gb = wt + (size_t)(tc + srow) * EMBED + scol;

#define GISSUE(k0_, bi_) do { \
    __builtin_amdgcn_global_load_lds(GLB(ga + (k0_)),              LDSP(&Al[bi_][0] + wave * 1024),       16, 0, 0); \
    __builtin_amdgcn_global_load_lds(GLB(ga + (k0_) + 16 * EMBED), LDSP(&Al[bi_][0] + wave * 1024 + 512), 16, 0, 0); \
    __builtin_amdgcn_global_load_lds(GLB(gb + (k0_)),              LDSP(&Bl[bi_][0] + wave * 1024),       16, 0, 0); \
    __builtin_amdgcn_global_load_lds(GLB(gb + (k0_) + 16 * EMBED), LDSP(&Bl[bi_][0] + wave * 1024 + 512), 16, 0, 0); \
} while (0)

    f32x4 acc[4][4] = {};
    GISSUE(0, 0);
    for (int k0 = 0; k0 < EMBED; k0 += 32) {
        const int cur = (k0 >> 5) & 1;
        asm volatile("s_waitcnt vmcnt(0)" ::: "memory");
        __builtin_amdgcn_s_barrier();
        if (k0 + 32 < EMBED) GISSUE(k0 + 32, cur ^ 1);
        __builtin_amdgcn_sched_barrier(0);
        const unsigned short* Ac = &Al[cur][0];
        const unsigned short* Bc = &Bl[cur][0];
        bf16x8 af[4], bfr[4];
        #pragma unroll
        for (int m = 0; m < 4; m++) af[m]  = *(const bf16x8*)&Ac[(wr * 64 + m * 16 + l15) * 32 + l4 * 8];
        #pragma unroll
        for (int n = 0; n < 4; n++) bfr[n] = *(const bf16x8*)&Bc[(wc * 64 + n * 16 + l15) * 32 + l4 * 8];
        #pragma unroll
        for (int m = 0; m < 4; m++)
            #pragma unroll
            for (int n = 0; n < 4; n++)
                acc[m][n] = MFMA(af[m], bfr[n], acc[m][n]);
    }
#undef GISSUE

    #pragma unroll
    for (int m = 0; m < 4; m++)
        #pragma unroll
        for (int j = 0; j < 4; j++) {
            int row = tm + wr * 64 + m * 16 + l4 * 4 + j;
            #pragma unroll
            for (int n = 0; n < 4; n++) {
                int col = tc + wc * 64 + n * 16 + l15;
                out[(size_t)row * EMBED + col] = acc[m][n][j] + bias[col];
            }
        }
}

extern "C" void kernel_launch(void* const* d_in, const int* in_sizes, int n_in,
                              void* d_out, int out_size, void* d_ws, size_t ws_size,
                              hipStream_t stream) {
    const float* x     = (const float*)d_in[0];
    const float* rc    = (const float*)d_in[1];
    const float* rs    = (const float*)d_in[2];
    const float* Wqkv  = (const float*)d_in[3];
    const float* bqkv  = (const float*)d_in[4];
    const float* Wproj = (const float*)d_in[5];
    const float* bproj = (const float*)d_in[6];
    char* ws = (char*)d_ws;
    // workspace layout (75.5 MB): xb region is reused for attention output
    unsigned short* xb  = (unsigned short*)(ws);                 // 16.78MB : x bf16, later attn-O bf16
    unsigned short* wqt = (unsigned short*)(ws + 16777216);      //  6.29MB : Wqkv^T bf16
    unsigned short* wpt = (unsigned short*)(ws + 23068672);      //  2.10MB : Wproj^T bf16
    unsigned short* Qb  = (unsigned short*)(ws + 25165824);      // 16.78MB : Q (roped, prescaled by QSCALE)
    unsigned short* Kb  = (unsigned short*)(ws + 41943040);      // 16.78MB : K (roped)
    unsigned short* Vt  = (unsigned short*)(ws + 58720256);      // 16.78MB : V^T
    float* outp = (float*)d_out;

    k_convert  <<<8192, 256, 0, stream>>>(x, xb, 2097152);
    k_transpose<<<dim3(96, 32), 256, 0, stream>>>(Wqkv, wqt, 1024, 3072);
    k_transpose<<<dim3(32, 32), 256, 0, stream>>>(Wproj, wpt, 1024, 1024);
    k_qkv      <<<dim3(24, 64), 256, 0, stream>>>(xb, wqt, bqkv, rc, rs, Qb, Kb, Vt);
    k_attn     <<<dim3(16, 64), 256, 0, stream>>>(Qb, Kb, Vt, xb);
    k_proj     <<<dim3(8, 64),  256, 0, stream>>>(xb, wpt, bproj, outp);
}